// Round 2
// baseline (652.679 us; speedup 1.0000x reference)
//
#include <hip/hip_runtime.h>
#include <hip/hip_bf16.h>

// PairwiseAttention: z(1,256,256,128) -> LN -> QKV -> 4-head attn (over 2nd L axis)
// -> proj + residual.  Input/output dtype is runtime-sniffed (bf16 vs fp32):
// decoding fp32 data as bf16 produced NaN in round 1; the harness label "bf16"
// is hard-coded and proves nothing. Both paths are compiled; blocks early-exit
// on the inactive one (deterministic, graph-safe).

__device__ __forceinline__ float bflo(unsigned int u) { return __uint_as_float(u << 16); }
__device__ __forceinline__ float bfhi(unsigned int u) { return __uint_as_float(u & 0xffff0000u); }
__device__ __forceinline__ float bf2f(unsigned short u) { return __uint_as_float(((unsigned int)u) << 16); }
__device__ __forceinline__ unsigned short f2bf(float f) {
    unsigned int i = __float_as_uint(f);
    i += 0x7fffu + ((i >> 16) & 1u);           // round-to-nearest-even
    return (unsigned short)(i >> 16);
}

// Decide whether the buffer holds fp32 (true) or bf16 (false) data.
// For bf16 data, the low 16 bits of each dword are a genuine ~N(0,1) bf16 value.
// For fp32 data, they are mantissa bits -> as bf16 the exponent is ~uniform ->
// mostly extreme magnitudes. Vote over 64 dwords; identical in every block.
__device__ bool sniff_is_f32(const unsigned int* z) {
    int n = 0;
    for (int i = 0; i < 64; ++i) {
        float a = fabsf(bflo(z[i]));
        n += (int)(a > 1e4f) | (int)(a > 0.f && a < 1e-6f);
    }
    return n > 16;
}

template<bool F32> __device__ __forceinline__ float ldel(const void* p, int i) {
    if constexpr (F32) return ((const float*)p)[i];
    else               return bf2f(((const unsigned short*)p)[i]);
}
template<bool F32> __device__ __forceinline__ void ld8(const void* p, int i8, float* v) {
    if constexpr (F32) {
        const float4* q = (const float4*)p;
        float4 a = q[2 * i8], b = q[2 * i8 + 1];
        v[0]=a.x; v[1]=a.y; v[2]=a.z; v[3]=a.w; v[4]=b.x; v[5]=b.y; v[6]=b.z; v[7]=b.w;
    } else {
        uint4 u = ((const uint4*)p)[i8];
        const unsigned int* pu = (const unsigned int*)&u;
        #pragma unroll
        for (int j = 0; j < 4; ++j) { v[2*j] = bflo(pu[j]); v[2*j+1] = bfhi(pu[j]); }
    }
}
template<bool F32> __device__ __forceinline__ void st8(void* p, int i8, const float* v) {
    if constexpr (F32) {
        float4 a, b;
        a.x=v[0]; a.y=v[1]; a.z=v[2]; a.w=v[3];
        b.x=v[4]; b.y=v[5]; b.z=v[6]; b.w=v[7];
        ((float4*)p)[2 * i8] = a; ((float4*)p)[2 * i8 + 1] = b;
    } else {
        uint4 u; unsigned int* pu = (unsigned int*)&u;
        #pragma unroll
        for (int j = 0; j < 4; ++j)
            pu[j] = (unsigned int)f2bf(v[2*j]) | ((unsigned int)f2bf(v[2*j+1]) << 16);
        ((uint4*)p)[i8] = u;
    }
}
template<bool F32> __device__ __forceinline__ const void* elptr(const void* p, size_t off) {
    if constexpr (F32) return (const void*)((const float*)p + off);
    else               return (const void*)((const unsigned short*)p + off);
}
template<bool F32> __device__ __forceinline__ void* elptrw(void* p, size_t off) {
    if constexpr (F32) return (void*)((float*)p + off);
    else               return (void*)((unsigned short*)p + off);
}

// ---------------- Kernel A: LN + QKV slice + flash attention per (r, h) ----------------
// grid = 1024 (r*4+h), block = 256 (one thread per query position p)
template<bool F32>
__global__ __launch_bounds__(256) void attn_fused(
    const void* __restrict__ z, const void* __restrict__ ln_g, const void* __restrict__ ln_b,
    const void* __restrict__ w_qkv, const void* __restrict__ b_qkv, void* __restrict__ out)
{
    if (sniff_is_f32((const unsigned int*)z) != F32) return;

    __shared__ float smem[16384];   // 64 KB union: phase1 = w'[128][96]+bias[96]; phase2 = kv[256][64]
    float* wp = smem;
    float* bias = smem + 12288;

    const int t = threadIdx.x;
    const int r = blockIdx.x >> 2;
    const int h = blockIdx.x & 3;

    // stage w' = g ⊙ (W_qkv slice for head h): local col c -> global col (c/32)*128 + h*32 + (c%32)
    for (int idx = t; idx < 6144; idx += 256) {
        int k = idx / 48;
        int j = idx - k * 48;
        int c = 2 * j;
        int gc = ((c >> 5) << 7) + (h << 5) + (c & 31);
        float g = ldel<F32>(ln_g, k);
        wp[k * 96 + c]     = g * ldel<F32>(w_qkv, k * 384 + gc);
        wp[k * 96 + c + 1] = g * ldel<F32>(w_qkv, k * 384 + gc + 1);
    }
    if (t < 96) {  // bias_c = b_qkv[gc] + sum_k ln_b[k] * W[k][gc]
        int gc = ((t >> 5) << 7) + (h << 5) + (t & 31);
        float b = ldel<F32>(b_qkv, gc);
        for (int k = 0; k < 128; ++k)
            b += ldel<F32>(ln_b, k) * ldel<F32>(w_qkv, k * 384 + gc);
        bias[t] = b;
    }

    // per-thread LN stats for row p = t
    const void* zrow = elptr<F32>(z, ((size_t)r * 256 + t) << 7);
    float sum = 0.f, sumsq = 0.f;
    #pragma unroll 1
    for (int i = 0; i < 16; ++i) {
        float v[8]; ld8<F32>(zrow, i, v);
        #pragma unroll
        for (int j = 0; j < 8; ++j) { sum += v[j]; sumsq += v[j] * v[j]; }
    }
    const float mu   = sum * (1.f / 128.f);
    const float rsig = 1.0f / sqrtf(sumsq * (1.f / 128.f) - mu * mu + 1e-5f);
    const float nb   = -mu * rsig;          // zh = z*rsig + nb

    __syncthreads();

    float acc[96];
    #pragma unroll
    for (int c = 0; c < 96; ++c) acc[c] = bias[c];

    #pragma unroll 1
    for (int i = 0; i < 16; ++i) {
        float v[8]; ld8<F32>(zrow, i, v);
        #pragma unroll
        for (int j = 0; j < 8; ++j) {
            float zh = fmaf(v[j], rsig, nb);
            const float4* wr = (const float4*)&wp[(i * 8 + j) * 96];
            #pragma unroll
            for (int c4 = 0; c4 < 24; ++c4) {
                float4 w4 = wr[c4];
                acc[c4*4+0] = fmaf(zh, w4.x, acc[c4*4+0]);
                acc[c4*4+1] = fmaf(zh, w4.y, acc[c4*4+1]);
                acc[c4*4+2] = fmaf(zh, w4.z, acc[c4*4+2]);
                acc[c4*4+3] = fmaf(zh, w4.w, acc[c4*4+3]);
            }
        }
    }

    const float scale = 0.17677669529663689f;  // 1/sqrt(32), folded into q
    float q[32];
    #pragma unroll
    for (int d = 0; d < 32; ++d) q[d] = acc[d] * scale;

    __syncthreads();                 // everyone done reading wp
    float* kv = smem;                // [256][64]: k at [p][0..31], v at [p][32..63]
    #pragma unroll
    for (int d4 = 0; d4 < 8; ++d4) {
        float4 kk; kk.x = acc[32+d4*4]; kk.y = acc[33+d4*4]; kk.z = acc[34+d4*4]; kk.w = acc[35+d4*4];
        ((float4*)&kv[t * 64])[d4] = kk;
        float4 vv; vv.x = acc[64+d4*4]; vv.y = acc[65+d4*4]; vv.z = acc[66+d4*4]; vv.w = acc[67+d4*4];
        ((float4*)&kv[t * 64 + 32])[d4] = vv;
    }
    __syncthreads();

    // flash loop (online softmax), all kv reads are wave-uniform broadcasts
    float m = -3.0e38f, lsum = 0.f;
    float o[32];
    #pragma unroll
    for (int d = 0; d < 32; ++d) o[d] = 0.f;

    #pragma unroll 1
    for (int j = 0; j < 256; ++j) {
        const float4* kj = (const float4*)&kv[j * 64];
        float s = 0.f;
        #pragma unroll
        for (int d4 = 0; d4 < 8; ++d4) {
            float4 k4 = kj[d4];
            s = fmaf(q[d4*4+0], k4.x, s);
            s = fmaf(q[d4*4+1], k4.y, s);
            s = fmaf(q[d4*4+2], k4.z, s);
            s = fmaf(q[d4*4+3], k4.w, s);
        }
        if (s > m) {
            float alpha = __expf(fmaxf(m - s, -87.f));   // clamped: safe even vs -3e38 sentinel
            lsum *= alpha;
            #pragma unroll
            for (int d = 0; d < 32; ++d) o[d] *= alpha;
            m = s;
        }
        float w = __expf(s - m);     // s - m <= 0 always
        lsum += w;
        const float4* vj = (const float4*)&kv[j * 64 + 32];
        #pragma unroll
        for (int d4 = 0; d4 < 8; ++d4) {
            float4 v4 = vj[d4];
            o[d4*4+0] = fmaf(w, v4.x, o[d4*4+0]);
            o[d4*4+1] = fmaf(w, v4.y, o[d4*4+1]);
            o[d4*4+2] = fmaf(w, v4.z, o[d4*4+2]);
            o[d4*4+3] = fmaf(w, v4.w, o[d4*4+3]);
        }
    }
    const float rl = 1.f / lsum;

    void* orow = elptrw<F32>(out, (((size_t)r * 256 + t) << 7) + (h << 5));
    #pragma unroll
    for (int i = 0; i < 4; ++i) {
        float v[8];
        #pragma unroll
        for (int j = 0; j < 8; ++j) v[j] = o[i*8 + j] * rl;
        st8<F32>(orow, i, v);
    }
}

// ---------------- Kernel B: out = z + attnout @ w_proj + b_proj (in-place on d_out) ----------------
// grid = 4096 (16 rows each), block = 256
template<bool F32>
__global__ __launch_bounds__(256) void proj_res(
    const void* __restrict__ z, const void* __restrict__ w_proj, const void* __restrict__ b_proj,
    void* __restrict__ out)
{
    if (sniff_is_f32((const unsigned int*)z) != F32) return;

    __shared__ unsigned int wu[8192];   // packed bf16 pairs (bf16 mode only)
    __shared__ float aT[128][20];       // [k][row] transposed a-tile, reused as out stage

    const int t = threadIdx.x;
    const size_t row0 = (size_t)blockIdx.x * 16;

    if constexpr (!F32) {
        for (int idx = t; idx < 8192; idx += 256)
            wu[idx] = ((const unsigned int*)w_proj)[idx];
    }

    {   // stage attnout tile (coalesced reads), transpose into aT
        const int rr = t >> 4;
        const int i8 = t & 15;
        float v[8];
        ld8<F32>(elptr<F32>((const void*)out, (row0 + rr) * 128), i8, v);
        #pragma unroll
        for (int j = 0; j < 8; ++j) aT[(i8 << 3) + j][rr] = v[j];
    }
    __syncthreads();

    const int c = t & 127;
    const int half = t >> 7;
    float acc8[8];
    const float bp = ldel<F32>(b_proj, c);
    #pragma unroll
    for (int rr = 0; rr < 8; ++rr) acc8[rr] = bp;

    #pragma unroll 1
    for (int k = 0; k < 128; ++k) {
        float wk;
        if constexpr (F32) {
            wk = ((const float*)w_proj)[k * 128 + c];   // coalesced, L1/L2-hot
        } else {
            unsigned int u = wu[(k << 6) + (c >> 1)];
            wk = (c & 1) ? bfhi(u) : bflo(u);
        }
        const float4 a0 = *(const float4*)&aT[k][half * 8];
        const float4 a1 = *(const float4*)&aT[k][half * 8 + 4];
        acc8[0] = fmaf(a0.x, wk, acc8[0]);
        acc8[1] = fmaf(a0.y, wk, acc8[1]);
        acc8[2] = fmaf(a0.z, wk, acc8[2]);
        acc8[3] = fmaf(a0.w, wk, acc8[3]);
        acc8[4] = fmaf(a1.x, wk, acc8[4]);
        acc8[5] = fmaf(a1.y, wk, acc8[5]);
        acc8[6] = fmaf(a1.z, wk, acc8[6]);
        acc8[7] = fmaf(a1.w, wk, acc8[7]);
    }
    __syncthreads();
    float* ot = (float*)aT;             // reuse as [16][128] out stage
    #pragma unroll
    for (int rr = 0; rr < 8; ++rr)
        ot[(half * 8 + rr) * 128 + c] = acc8[rr];
    __syncthreads();

    {   // coalesced final write: + residual z
        const int rr = t >> 4;
        const int i8 = t & 15;
        float zv[8], v[8];
        ld8<F32>(elptr<F32>(z, (row0 + rr) * 128), i8, zv);
        const float* po = &ot[rr * 128 + (i8 << 3)];
        #pragma unroll
        for (int j = 0; j < 8; ++j) v[j] = po[j] + zv[j];
        st8<F32>(elptrw<F32>(out, (row0 + rr) * 128), i8, v);
    }
}

extern "C" void kernel_launch(void* const* d_in, const int* in_sizes, int n_in,
                              void* d_out, int out_size, void* d_ws, size_t ws_size,
                              hipStream_t stream) {
    const void* z      = d_in[0];
    const void* ln_g   = d_in[1];
    const void* ln_b   = d_in[2];
    const void* w_qkv  = d_in[3];
    const void* b_qkv  = d_in[4];
    const void* w_proj = d_in[5];
    const void* b_proj = d_in[6];
    void* out = d_out;

    attn_fused<false><<<1024, 256, 0, stream>>>(z, ln_g, ln_b, w_qkv, b_qkv, out);
    attn_fused<true ><<<1024, 256, 0, stream>>>(z, ln_g, ln_b, w_qkv, b_qkv, out);
    proj_res<false><<<4096, 256, 0, stream>>>(z, w_proj, b_proj, out);
    proj_res<true ><<<4096, 256, 0, stream>>>(z, w_proj, b_proj, out);
}